// Round 8
// baseline (118.314 us; speedup 1.0000x reference)
//
#include <hip/hip_runtime.h>
#include <math.h>

#define N 4096
#define D 128
#define P 16
#define KK 2048                    // P*D, single f16 plane
#define NTB 16                     // 256-wide tiles per dim
#define NBLK (NTB * NTB)           // full grid: 256 blocks = 1/CU
#define LCAPD 15000                // worklist capacity in aliased staging LDS
#define CAP (1u << 20)             // global worklist capacity (4 MB)
#define WIN 1.5e-3f                // > 1.1e-3 rigorous scaled-f16 bound
#define ZSCALE 256.0f              // 2^8, exact
#define OSCALE (1.0f / 16777216.0f * 16.0f)  // 0.0625 * 2^-16 = 2^-20, exact

typedef _Float16 half_t;
typedef __attribute__((ext_vector_type(8))) _Float16 f16x8;
typedef __attribute__((ext_vector_type(4))) float f32x4;
typedef __attribute__((address_space(1))) const unsigned int* gptr_t;
typedef __attribute__((address_space(3))) unsigned int* lptr_t;

// ---------------------------------------------------------------------------
// K1: fused norms (f64, cross-lane reduce) + scaled f16 pack + counter init.
// ---------------------------------------------------------------------------
__global__ __launch_bounds__(256) void k_pack(const float* __restrict__ c,
                                              const float* __restrict__ w,
                                              double* __restrict__ rnorm,
                                              half_t* __restrict__ zb,
                                              unsigned* gcnt, unsigned* govf,
                                              int do_init) {
    int n = blockIdx.x, tid = threadIdx.x;
    if (do_init && n == 0 && tid == 0) { *gcnt = 0; *govf = 0; }
    int p = tid >> 4, d0 = (tid & 15) * 8;
    const float* cc = c + (size_t)n * D + d0;
    const float* ww = w + (size_t)p * D + d0;
    float cv[8], wv[8];
    *(float4*)&cv[0] = *(const float4*)&cc[0];
    *(float4*)&cv[4] = *(const float4*)&cc[4];
    *(float4*)&wv[0] = *(const float4*)&ww[0];
    *(float4*)&wv[4] = *(const float4*)&ww[4];
    double s = 0.0;
#pragma unroll
    for (int i = 0; i < 8; ++i) {
        double v = (double)cv[i] * (double)wv[i];
        s += v * v;
    }
#pragma unroll
    for (int o = 1; o < 16; o <<= 1) s += __shfl_xor(s, o, 64);
    double rn = 1.0 / fmax(sqrt(s), 1e-12);
    if ((tid & 15) == 0) rnorm[p * N + n] = rn;
    float rnf = (float)rn;
    f16x8 o8;
#pragma unroll
    for (int i = 0; i < 8; ++i) o8[i] = (half_t)(cv[i] * wv[i] * rnf * ZSCALE);
    *(f16x8*)&zb[(size_t)n * KK + tid * 8] = o8;
}

// ---------------------------------------------------------------------------
// K2: f16 MFMA GEMM out = Z Z^T / 16, fused mask + boundary worklist.
// 256x256 tile, BK=32, 8 waves (2M x 4N; wave tile 128x64), full grid (256
// blocks = 1/CU; symmetry dropped: at 1 block/CU, wall time == full grid and
// the mirror epilogue disappears). Counted-vmcnt double buffer:
//   STAGE(buf^1, kt+1)[4 gload_lds] -> vmcnt(4) -> s_barrier
//   -> 12 ds_read_b128 + 2x16 MFMA (setprio) -> lgkmcnt(0) -> s_barrier
// Loads get a full 64-MFMA K-tile (~600 cyc) to fly; vmcnt never 0 in loop.
// LDS: 64 KB static, 2 buf x (A[256][32] + B[256][32]) f16. Swizzle
// sigma(row) = (row>>1)&3 (64B rows) on stage-source and read (involution).
// reads/MFMA = 0.375 (12 b128 per 32 MFMA per wave) vs 0.5 in the 128^2 form.
// ---------------------------------------------------------------------------
template <bool FUSED>
__global__ __launch_bounds__(512, 2) void k_gemm(const half_t* __restrict__ zb,
                                                 float* __restrict__ out,
                                                 unsigned* __restrict__ gcnt,
                                                 unsigned* __restrict__ govf,
                                                 unsigned* __restrict__ glist) {
    __shared__ __align__(16) half_t smbuf[2][16384];   // 64 KB: [buf][A 8192 | B 8192]
    __shared__ unsigned wl3[4];                        // cnt, base, tot

    int tid = threadIdx.x;
    int lane = tid & 63, wid = tid >> 6;
    int wm = wid >> 2, wn = wid & 3;                   // 2M x 4N wave grid

    // XCD-chunked bijective swizzle (256 = 8 x 32)
    int braw = blockIdx.x;
    int b = (braw & 7) * 32 + (braw >> 3);
    int bi = b >> 4, bj = b & 15;
    int n0 = bi * 256, m0 = bj * 256;

    int rsel = lane & 15, kk_c = lane >> 4;
    int pc8 = (kk_c ^ ((rsel >> 1) & 3)) * 8;          // swizzled read chunk (f16 idx)

    int srow = tid >> 2;                               // staging row 0..127
    int schunk8 = ((tid & 3) ^ ((tid >> 3) & 3)) * 8;  // pre-swizzled source chunk

    f32x4 acc[8][4] = {};

    auto STAGE = [&](int p, int kt) {                  // 4 gload_lds per thread
        int k0 = kt * 32;
        half_t* A = &smbuf[p][0];
        half_t* B = &smbuf[p][8192];
        __builtin_amdgcn_global_load_lds(
            (gptr_t)(zb + (size_t)(n0 + srow) * KK + k0 + schunk8),
            (lptr_t)(A + tid * 8), 16, 0, 0);
        __builtin_amdgcn_global_load_lds(
            (gptr_t)(zb + (size_t)(n0 + 128 + srow) * KK + k0 + schunk8),
            (lptr_t)(A + 4096 + tid * 8), 16, 0, 0);
        __builtin_amdgcn_global_load_lds(
            (gptr_t)(zb + (size_t)(m0 + srow) * KK + k0 + schunk8),
            (lptr_t)(B + tid * 8), 16, 0, 0);
        __builtin_amdgcn_global_load_lds(
            (gptr_t)(zb + (size_t)(m0 + 128 + srow) * KK + k0 + schunk8),
            (lptr_t)(B + 4096 + tid * 8), 16, 0, 0);
    };

    STAGE(0, 0);
    asm volatile("s_waitcnt vmcnt(0)" ::: "memory");
    __builtin_amdgcn_sched_barrier(0);
    __builtin_amdgcn_s_barrier();
    __builtin_amdgcn_sched_barrier(0);

#pragma unroll 2
    for (int kt = 0; kt < 64; ++kt) {
        int p = kt & 1;
        if (kt < 63) {
            STAGE(p ^ 1, kt + 1);                      // next K-tile: issue EARLY
            asm volatile("s_waitcnt vmcnt(4)" ::: "memory");  // this tile's 4 done
        } else {
            asm volatile("s_waitcnt vmcnt(0)" ::: "memory");
        }
        __builtin_amdgcn_sched_barrier(0);
        __builtin_amdgcn_s_barrier();                  // all waves: buf[p] ready
        __builtin_amdgcn_sched_barrier(0);

        const half_t* A = &smbuf[p][0];
        const half_t* B = &smbuf[p][8192];
        f16x8 af[4], bfr[4];
#pragma unroll
        for (int fj = 0; fj < 4; ++fj)
            bfr[fj] = *(const f16x8*)&B[(wn * 64 + fj * 16 + rsel) * 32 + pc8];
#pragma unroll
        for (int fi = 0; fi < 4; ++fi)
            af[fi] = *(const f16x8*)&A[(wm * 128 + fi * 16 + rsel) * 32 + pc8];
        __builtin_amdgcn_s_setprio(1);
#pragma unroll
        for (int fi = 0; fi < 4; ++fi)
#pragma unroll
            for (int fj = 0; fj < 4; ++fj)
                acc[fi][fj] = __builtin_amdgcn_mfma_f32_16x16x32_f16(af[fi], bfr[fj], acc[fi][fj], 0, 0, 0);
        __builtin_amdgcn_s_setprio(0);
#pragma unroll
        for (int fi = 0; fi < 4; ++fi)
            af[fi] = *(const f16x8*)&A[(wm * 128 + 64 + fi * 16 + rsel) * 32 + pc8];
        __builtin_amdgcn_s_setprio(1);
#pragma unroll
        for (int fi = 0; fi < 4; ++fi)
#pragma unroll
            for (int fj = 0; fj < 4; ++fj)
                acc[4 + fi][fj] = __builtin_amdgcn_mfma_f32_16x16x32_f16(af[fi], bfr[fj], acc[4 + fi][fj], 0, 0, 0);
        __builtin_amdgcn_s_setprio(0);

        asm volatile("s_waitcnt lgkmcnt(0)" ::: "memory");  // my ds_reads done
        __builtin_amdgcn_sched_barrier(0);
        __builtin_amdgcn_s_barrier();                  // reads done -> overwrite ok
        __builtin_amdgcn_sched_barrier(0);
    }

    // staging LDS is dead -> alias as worklist
    unsigned* lds_list = (unsigned*)&smbuf[0][0];
    if (FUSED) {
        if (tid == 0) wl3[0] = 0;
        __syncthreads();
    }

    int colD = rsel, rq = kk_c;
#pragma unroll
    for (int fi = 0; fi < 8; ++fi)
#pragma unroll
        for (int fj = 0; fj < 4; ++fj) {
            int rbase = n0 + wm * 128 + fi * 16 + rq * 4;
            int ccol = m0 + wn * 64 + fj * 16 + colD;
#pragma unroll
            for (int q = 0; q < 4; ++q) {
                float a = acc[fi][fj][q] * OSCALE;
                float sv;
                if (FUSED) {
                    bool flg = fabsf(a - 0.1f) < WIN;
                    sv = flg ? a : (a > 0.1f ? a : 0.0f);
                    if (flg) {
                        unsigned pos = atomicAdd(&wl3[0], 1u);
                        if (pos < LCAPD)
                            lds_list[pos] = (unsigned)(rbase + q) | ((unsigned)ccol << 12);
                    }
                } else {
                    sv = a;
                }
                out[(size_t)(rbase + q) * N + ccol] = sv;
            }
        }

    if (FUSED) {
        __syncthreads();
        if (tid == 0) {
            unsigned tot = wl3[0];
            unsigned cnt = tot > LCAPD ? LCAPD : tot;
            wl3[2] = cnt;
            wl3[1] = atomicAdd(gcnt, cnt);
            if (tot > LCAPD) atomicOr(govf, 1u);
        }
        __syncthreads();
        unsigned cnt = wl3[2], base = wl3[1];
        for (unsigned e = tid; e < cnt; e += 512) {
            unsigned gi = base + e;
            if (gi < CAP) glist[gi] = lds_list[e];
            else atomicOr(govf, 1u);
        }
    }
}

// ---------------------------------------------------------------------------
// K3: exact f64 recompute of worklist entries — one entry per lane, 16
// independent f64 accumulators, float4 gathers, LDS-broadcast w^2.
// ---------------------------------------------------------------------------
__global__ __launch_bounds__(256) void k_fix2(const float* __restrict__ c,
                                              const float* __restrict__ w,
                                              const double* __restrict__ rnorm,
                                              const unsigned* __restrict__ gcnt,
                                              const unsigned* __restrict__ glist,
                                              float* __restrict__ out) {
    __shared__ double w2[D * P];   // w2[d*16+p], 16 KB
    for (int e = threadIdx.x; e < P * D; e += 256) {
        int p = e >> 7, d = e & 127;
        double wv = (double)w[p * D + d];
        w2[d * P + p] = wv * wv;
    }
    __syncthreads();

    unsigned count = *gcnt;
    if (count > CAP) count = CAP;
    unsigned stride = gridDim.x * 256;
    for (unsigned e = blockIdx.x * 256 + threadIdx.x; e < count; e += stride) {
        unsigned u = glist[e];
        int n = u & 4095, m = (u >> 12) & 4095;
        const float* cn = c + (size_t)n * D;
        const float* cm = c + (size_t)m * D;
        double acc[P];
#pragma unroll
        for (int p = 0; p < P; ++p) acc[p] = 0.0;
        for (int d0 = 0; d0 < D; d0 += 4) {
            float4 a4 = *(const float4*)&cn[d0];
            float4 b4 = *(const float4*)&cm[d0];
            float av[4] = {a4.x, a4.y, a4.z, a4.w};
            float bv[4] = {b4.x, b4.y, b4.z, b4.w};
#pragma unroll
            for (int q = 0; q < 4; ++q) {
                double pr = (double)av[q] * (double)bv[q];
#pragma unroll
                for (int p = 0; p < P; ++p) acc[p] += pr * w2[(d0 + q) * P + p];
            }
        }
        double t = 0.0;
#pragma unroll
        for (int p = 0; p < P; ++p)
            t += acc[p] * (rnorm[p * N + n] * rnorm[p * N + m]);
        double fin = t * 0.0625;
        float res = (fin > 0.1) ? (float)fin : 0.0f;
        out[(size_t)n * N + m] = res;
        if (u >> 24) out[(size_t)m * N + n] = res;
    }
}

// ---------------------------------------------------------------------------
// K4: overflow guard — full-pass resolve, only if worklist overflowed.
// ---------------------------------------------------------------------------
__global__ __launch_bounds__(256) void k_guard(const float* __restrict__ c,
                                               const float* __restrict__ w,
                                               const double* __restrict__ rnorm,
                                               const unsigned* __restrict__ govf,
                                               float* __restrict__ out) {
    if (*govf == 0) return;
    __shared__ double w2[D * P];
    for (int e = threadIdx.x; e < P * D; e += 256) {
        int p = e >> 7, d = e & 127;
        double wv = (double)w[p * D + d];
        w2[d * P + p] = wv * wv;
    }
    __syncthreads();
    size_t stride = (size_t)gridDim.x * 256;
    for (size_t idx = (size_t)blockIdx.x * 256 + threadIdx.x; idx < (size_t)N * N;
         idx += stride) {
        float a = out[idx];
        if (fabsf(a - 0.1f) >= WIN) {
            out[idx] = (a > 0.1f) ? a : 0.0f;
            continue;
        }
        int n = (int)(idx >> 12), m = (int)(idx & (N - 1));
        const float* cn = c + (size_t)n * D;
        const float* cm = c + (size_t)m * D;
        double acc[P];
#pragma unroll
        for (int p = 0; p < P; ++p) acc[p] = 0.0;
        for (int d0 = 0; d0 < D; d0 += 4) {
            float4 a4 = *(const float4*)&cn[d0];
            float4 b4 = *(const float4*)&cm[d0];
            float av[4] = {a4.x, a4.y, a4.z, a4.w};
            float bv[4] = {b4.x, b4.y, b4.z, b4.w};
#pragma unroll
            for (int q = 0; q < 4; ++q) {
                double pr = (double)av[q] * (double)bv[q];
#pragma unroll
                for (int p = 0; p < P; ++p) acc[p] += pr * w2[(d0 + q) * P + p];
            }
        }
        double t = 0.0;
#pragma unroll
        for (int p = 0; p < P; ++p)
            t += acc[p] * (rnorm[p * N + n] * rnorm[p * N + m]);
        double fin = t * 0.0625;
        out[idx] = (fin > 0.1) ? (float)fin : 0.0f;
    }
}

// ---------------------------------------------------------------------------
// Fallback full-pass mask fix (only if ws too small; proven not taken).
// ---------------------------------------------------------------------------
__global__ __launch_bounds__(256) void k_fix_full(const float* __restrict__ c,
                                                  const float* __restrict__ w,
                                                  const double* __restrict__ rnorm,
                                                  float* __restrict__ out) {
    __shared__ double w2[D * P];
    for (int e = threadIdx.x; e < P * D; e += 256) {
        int p = e >> 7, d = e & 127;
        double wv = (double)w[p * D + d];
        w2[d * P + p] = wv * wv;
    }
    __syncthreads();
    size_t stride = (size_t)gridDim.x * 256;
    for (size_t idx = (size_t)blockIdx.x * 256 + threadIdx.x; idx < (size_t)N * N;
         idx += stride) {
        float a = out[idx];
        if (fabsf(a - 0.1f) >= WIN) {
            out[idx] = (a > 0.1f) ? a : 0.0f;
            continue;
        }
        int n = (int)(idx >> 12), m = (int)(idx & (N - 1));
        const float* cn = c + (size_t)n * D;
        const float* cm = c + (size_t)m * D;
        double acc[P];
#pragma unroll
        for (int p = 0; p < P; ++p) acc[p] = 0.0;
        for (int d0 = 0; d0 < D; d0 += 4) {
            float4 a4 = *(const float4*)&cn[d0];
            float4 b4 = *(const float4*)&cm[d0];
            float av[4] = {a4.x, a4.y, a4.z, a4.w};
            float bv[4] = {b4.x, b4.y, b4.z, b4.w};
#pragma unroll
            for (int q = 0; q < 4; ++q) {
                double pr = (double)av[q] * (double)bv[q];
#pragma unroll
                for (int p = 0; p < P; ++p) acc[p] += pr * w2[(d0 + q) * P + p];
            }
        }
        double t = 0.0;
#pragma unroll
        for (int p = 0; p < P; ++p)
            t += acc[p] * (rnorm[p * N + n] * rnorm[p * N + m]);
        double fin = t * 0.0625;
        out[idx] = (fin > 0.1) ? (float)fin : 0.0f;
    }
}

// ---------------------------------------------------------------------------
extern "C" void kernel_launch(void* const* d_in, const int* in_sizes, int n_in,
                              void* d_out, int out_size, void* d_ws, size_t ws_size,
                              hipStream_t stream) {
    const float* c = (const float*)d_in[0];
    const float* w = (const float*)d_in[1];
    float* out = (float*)d_out;
    char* ws = (char*)d_ws;

    double* rnorm = (double*)ws;                               // 512 KB
    size_t off = (size_t)P * N * 8;
    unsigned* gcnt = (unsigned*)(ws + off);
    unsigned* govf = gcnt + 1;
    unsigned* glist = (unsigned*)(ws + off + 128);             // 4 MB
    half_t* zb = (half_t*)(ws + off + 128 + (size_t)CAP * 4);  // 16 MB
    size_t need = off + 128 + (size_t)CAP * 4 + (size_t)N * KK * 2;

    if (ws_size >= need) {
        k_pack<<<N, 256, 0, stream>>>(c, w, rnorm, zb, gcnt, govf, 1);
        k_gemm<true><<<NBLK, 512, 0, stream>>>(zb, out, gcnt, govf, glist);
        k_fix2<<<1024, 256, 0, stream>>>(c, w, rnorm, gcnt, glist, out);
        k_guard<<<1024, 256, 0, stream>>>(c, w, rnorm, govf, out);
    } else {
        half_t* zb2 = (half_t*)(ws + off);
        k_pack<<<N, 256, 0, stream>>>(c, w, rnorm, zb2, nullptr, nullptr, 0);
        k_gemm<false><<<NBLK, 512, 0, stream>>>(zb2, out, nullptr, nullptr, nullptr);
        k_fix_full<<<4096, 256, 0, stream>>>(c, w, rnorm, out);
    }
}

// Round 9
// 107.899 us; speedup vs baseline: 1.0965x; 1.0965x over previous
//
#include <hip/hip_runtime.h>
#include <math.h>

#define N 4096
#define D 128
#define P 16
#define KK 2048                    // P*D, single f16 plane
#define NTB 16                     // 256-wide tiles per dim
#define NBLK (NTB * (NTB + 1) / 2) // 136 upper-tri blocks = 8 x 17
#define LCAPD 20000                // worklist capacity in aliased staging LDS
#define CAP (1u << 20)             // global worklist capacity (4 MB)
#define WIN 1.5e-3f                // > 1.1e-3 rigorous scaled-f16 bound
#define ZSCALE 256.0f              // 2^8, exact
#define OSCALE (1.0f / 16777216.0f * 16.0f)  // 0.0625 * 2^-16 = 2^-20, exact

typedef _Float16 half_t;
typedef __attribute__((ext_vector_type(8))) _Float16 f16x8;
typedef __attribute__((ext_vector_type(4))) float f32x4;
typedef __attribute__((address_space(1))) const unsigned int* gptr_t;
typedef __attribute__((address_space(3))) unsigned int* lptr_t;

// ---------------------------------------------------------------------------
// K1: fused norms (f64, cross-lane reduce) + scaled f16 pack + counter init.
// ---------------------------------------------------------------------------
__global__ __launch_bounds__(256) void k_pack(const float* __restrict__ c,
                                              const float* __restrict__ w,
                                              double* __restrict__ rnorm,
                                              half_t* __restrict__ zb,
                                              unsigned* gcnt, unsigned* govf,
                                              int do_init) {
    int n = blockIdx.x, tid = threadIdx.x;
    if (do_init && n == 0 && tid == 0) { *gcnt = 0; *govf = 0; }
    int p = tid >> 4, d0 = (tid & 15) * 8;
    const float* cc = c + (size_t)n * D + d0;
    const float* ww = w + (size_t)p * D + d0;
    float cv[8], wv[8];
    *(float4*)&cv[0] = *(const float4*)&cc[0];
    *(float4*)&cv[4] = *(const float4*)&cc[4];
    *(float4*)&wv[0] = *(const float4*)&ww[0];
    *(float4*)&wv[4] = *(const float4*)&ww[4];
    double s = 0.0;
#pragma unroll
    for (int i = 0; i < 8; ++i) {
        double v = (double)cv[i] * (double)wv[i];
        s += v * v;
    }
#pragma unroll
    for (int o = 1; o < 16; o <<= 1) s += __shfl_xor(s, o, 64);
    double rn = 1.0 / fmax(sqrt(s), 1e-12);
    if ((tid & 15) == 0) rnorm[p * N + n] = rn;
    float rnf = (float)rn;
    f16x8 o8;
#pragma unroll
    for (int i = 0; i < 8; ++i) o8[i] = (half_t)(cv[i] * wv[i] * rnf * ZSCALE);
    *(f16x8*)&zb[(size_t)n * KK + tid * 8] = o8;
}

// ---------------------------------------------------------------------------
// K2: f16 MFMA GEMM out = Z Z^T / 16, fused mask + boundary worklist.
// 256x256 tile, BK=32, 8 waves (2M x 4N; wave tile 128x64), TRIANGULAR grid
// (136 blocks; mirror via native float4 stores; total staged bytes halved
// vs full grid). Triple-buffered counted-vmcnt pipeline:
//   STAGE(buf[(kt+2)%3], kt+2)[4 gload_lds] -> vmcnt(8) -> s_barrier
//   -> 12 ds_read_b128 + 2x16 MFMA (setprio) -> lgkmcnt(0) -> s_barrier
// Loads get TWO full K-tile compute phases to fly; vmcnt never 0 in loop.
// LDS: 96 KB static (3 x 32KB buf). Swizzle sigma(row)=(row>>1)&3 on both
// stage-source and read (involution; verified conflict-free in r6/r7).
// ---------------------------------------------------------------------------
template <bool FUSED>
__global__ __launch_bounds__(512, 2) void k_gemm(const half_t* __restrict__ zb,
                                                 float* __restrict__ out,
                                                 unsigned* __restrict__ gcnt,
                                                 unsigned* __restrict__ govf,
                                                 unsigned* __restrict__ glist) {
    __shared__ __align__(16) half_t smbuf[3][16384];   // 96 KB: [buf][A 8192 | B 8192]
    __shared__ unsigned wl3[4];                        // cnt, base, tot

    int tid = threadIdx.x;
    int lane = tid & 63, wid = tid >> 6;
    int wm = wid >> 2, wn = wid & 3;                   // 2M x 4N wave grid

    // XCD-chunked bijective swizzle (136 = 8 x 17), then triangular decode
    int braw = blockIdx.x;
    int b = (braw & 7) * 17 + (braw >> 3);
    int ti = 0;
    while (b >= NTB - ti) { b -= NTB - ti; ++ti; }
    int tj = ti + b;
    int n0 = ti * 256, m0 = tj * 256;
    bool mir = (ti != tj);

    int rsel = lane & 15, kk_c = lane >> 4;
    int pc8 = (kk_c ^ ((rsel >> 1) & 3)) * 8;          // swizzled read chunk (f16 idx)

    int srow = tid >> 2;                               // staging row 0..127
    int schunk8 = ((tid & 3) ^ ((tid >> 3) & 3)) * 8;  // pre-swizzled source chunk

    f32x4 acc[8][4] = {};

    auto STAGE = [&](int p, int kt) {                  // 4 gload_lds per thread
        int k0 = kt * 32;
        half_t* A = &smbuf[p][0];
        half_t* B = &smbuf[p][8192];
        __builtin_amdgcn_global_load_lds(
            (gptr_t)(zb + (size_t)(n0 + srow) * KK + k0 + schunk8),
            (lptr_t)(A + tid * 8), 16, 0, 0);
        __builtin_amdgcn_global_load_lds(
            (gptr_t)(zb + (size_t)(n0 + 128 + srow) * KK + k0 + schunk8),
            (lptr_t)(A + 4096 + tid * 8), 16, 0, 0);
        __builtin_amdgcn_global_load_lds(
            (gptr_t)(zb + (size_t)(m0 + srow) * KK + k0 + schunk8),
            (lptr_t)(B + tid * 8), 16, 0, 0);
        __builtin_amdgcn_global_load_lds(
            (gptr_t)(zb + (size_t)(m0 + 128 + srow) * KK + k0 + schunk8),
            (lptr_t)(B + 4096 + tid * 8), 16, 0, 0);
    };

    auto COMPUTE = [&](int p) {
        const half_t* A = &smbuf[p][0];
        const half_t* B = &smbuf[p][8192];
        f16x8 af[4], bfr[4];
#pragma unroll
        for (int fj = 0; fj < 4; ++fj)
            bfr[fj] = *(const f16x8*)&B[(wn * 64 + fj * 16 + rsel) * 32 + pc8];
#pragma unroll
        for (int fi = 0; fi < 4; ++fi)
            af[fi] = *(const f16x8*)&A[(wm * 128 + fi * 16 + rsel) * 32 + pc8];
        __builtin_amdgcn_s_setprio(1);
#pragma unroll
        for (int fi = 0; fi < 4; ++fi)
#pragma unroll
            for (int fj = 0; fj < 4; ++fj)
                acc[fi][fj] = __builtin_amdgcn_mfma_f32_16x16x32_f16(af[fi], bfr[fj], acc[fi][fj], 0, 0, 0);
        __builtin_amdgcn_s_setprio(0);
#pragma unroll
        for (int fi = 0; fi < 4; ++fi)
            af[fi] = *(const f16x8*)&A[(wm * 128 + 64 + fi * 16 + rsel) * 32 + pc8];
        __builtin_amdgcn_s_setprio(1);
#pragma unroll
        for (int fi = 0; fi < 4; ++fi)
#pragma unroll
            for (int fj = 0; fj < 4; ++fj)
                acc[4 + fi][fj] = __builtin_amdgcn_mfma_f32_16x16x32_f16(af[fi], bfr[fj], acc[4 + fi][fj], 0, 0, 0);
        __builtin_amdgcn_s_setprio(0);
    };

#define VMW(nn) asm volatile("s_waitcnt vmcnt(" #nn ")" ::: "memory");        \
                __builtin_amdgcn_sched_barrier(0);                            \
                __builtin_amdgcn_s_barrier();                                 \
                __builtin_amdgcn_sched_barrier(0);
#define LGW     asm volatile("s_waitcnt lgkmcnt(0)" ::: "memory");            \
                __builtin_amdgcn_sched_barrier(0);                            \
                __builtin_amdgcn_s_barrier();                                 \
                __builtin_amdgcn_sched_barrier(0);

    STAGE(0, 0);
    STAGE(1, 1);

#pragma unroll 3
    for (int kt = 0; kt < 60; ++kt) {
        STAGE((kt + 2) % 3, kt + 2);   // two tiles ahead
        VMW(8)                          // kt's loads done; kt+1,kt+2 in flight
        COMPUTE(kt % 3);
        LGW
    }
    // peeled tail: kt = 60, 61, 62, 63
    STAGE(2, 62); VMW(8) COMPUTE(0); LGW
    STAGE(0, 63); VMW(8) COMPUTE(1); LGW
    VMW(4) COMPUTE(2); LGW
    VMW(0) COMPUTE(0);

#undef VMW
#undef LGW

    // staging LDS is dead -> alias as worklist
    unsigned* lds_list = (unsigned*)&smbuf[0][0];
    if (FUSED) {
        __syncthreads();
        if (tid == 0) wl3[0] = 0;
        __syncthreads();
    }

    int colD = rsel, rq = kk_c;
#pragma unroll
    for (int fi = 0; fi < 8; ++fi)
#pragma unroll
        for (int fj = 0; fj < 4; ++fj) {
            int rbase = n0 + wm * 128 + fi * 16 + rq * 4;
            int ccol = m0 + wn * 64 + fj * 16 + colD;
            float4 mv;
#pragma unroll
            for (int q = 0; q < 4; ++q) {
                float a = acc[fi][fj][q] * OSCALE;
                float sv;
                if (FUSED) {
                    bool flg = fabsf(a - 0.1f) < WIN;
                    sv = flg ? a : (a > 0.1f ? a : 0.0f);
                    if (flg) {
                        unsigned pos = atomicAdd(&wl3[0], 1u);
                        unsigned ent = (unsigned)(rbase + q) | ((unsigned)ccol << 12) |
                                       (mir ? (1u << 24) : 0u);
                        if (pos < LCAPD) lds_list[pos] = ent;
                    }
                } else {
                    sv = a;
                }
                out[(size_t)(rbase + q) * N + ccol] = sv;
                ((float*)&mv)[q] = sv;
            }
            if (mir) *(float4*)&out[(size_t)ccol * N + rbase] = mv;
        }

    if (FUSED) {
        __syncthreads();
        if (tid == 0) {
            unsigned tot = wl3[0];
            unsigned cnt = tot > LCAPD ? LCAPD : tot;
            wl3[2] = cnt;
            wl3[1] = atomicAdd(gcnt, cnt);
            if (tot > LCAPD) atomicOr(govf, 1u);
        }
        __syncthreads();
        unsigned cnt = wl3[2], base = wl3[1];
        for (unsigned e = tid; e < cnt; e += 512) {
            unsigned gi = base + e;
            if (gi < CAP) glist[gi] = lds_list[e];
            else atomicOr(govf, 1u);
        }
    }
}

// ---------------------------------------------------------------------------
// K3: exact f64 recompute of worklist entries — one entry per lane, 16
// independent f64 accumulators, float4 gathers, LDS-broadcast w^2.
// ---------------------------------------------------------------------------
__global__ __launch_bounds__(256) void k_fix2(const float* __restrict__ c,
                                              const float* __restrict__ w,
                                              const double* __restrict__ rnorm,
                                              const unsigned* __restrict__ gcnt,
                                              const unsigned* __restrict__ glist,
                                              float* __restrict__ out) {
    __shared__ double w2[D * P];   // w2[d*16+p], 16 KB
    for (int e = threadIdx.x; e < P * D; e += 256) {
        int p = e >> 7, d = e & 127;
        double wv = (double)w[p * D + d];
        w2[d * P + p] = wv * wv;
    }
    __syncthreads();

    unsigned count = *gcnt;
    if (count > CAP) count = CAP;
    unsigned stride = gridDim.x * 256;
    for (unsigned e = blockIdx.x * 256 + threadIdx.x; e < count; e += stride) {
        unsigned u = glist[e];
        int n = u & 4095, m = (u >> 12) & 4095;
        const float* cn = c + (size_t)n * D;
        const float* cm = c + (size_t)m * D;
        double acc[P];
#pragma unroll
        for (int p = 0; p < P; ++p) acc[p] = 0.0;
        for (int d0 = 0; d0 < D; d0 += 4) {
            float4 a4 = *(const float4*)&cn[d0];
            float4 b4 = *(const float4*)&cm[d0];
            float av[4] = {a4.x, a4.y, a4.z, a4.w};
            float bv[4] = {b4.x, b4.y, b4.z, b4.w};
#pragma unroll
            for (int q = 0; q < 4; ++q) {
                double pr = (double)av[q] * (double)bv[q];
#pragma unroll
                for (int p = 0; p < P; ++p) acc[p] += pr * w2[(d0 + q) * P + p];
            }
        }
        double t = 0.0;
#pragma unroll
        for (int p = 0; p < P; ++p)
            t += acc[p] * (rnorm[p * N + n] * rnorm[p * N + m]);
        double fin = t * 0.0625;
        float res = (fin > 0.1) ? (float)fin : 0.0f;
        out[(size_t)n * N + m] = res;
        if (u >> 24) out[(size_t)m * N + n] = res;
    }
}

// ---------------------------------------------------------------------------
// K4: overflow guard — full-pass resolve, only if worklist overflowed.
// ---------------------------------------------------------------------------
__global__ __launch_bounds__(256) void k_guard(const float* __restrict__ c,
                                               const float* __restrict__ w,
                                               const double* __restrict__ rnorm,
                                               const unsigned* __restrict__ govf,
                                               float* __restrict__ out) {
    if (*govf == 0) return;
    __shared__ double w2[D * P];
    for (int e = threadIdx.x; e < P * D; e += 256) {
        int p = e >> 7, d = e & 127;
        double wv = (double)w[p * D + d];
        w2[d * P + p] = wv * wv;
    }
    __syncthreads();
    size_t stride = (size_t)gridDim.x * 256;
    for (size_t idx = (size_t)blockIdx.x * 256 + threadIdx.x; idx < (size_t)N * N;
         idx += stride) {
        float a = out[idx];
        if (fabsf(a - 0.1f) >= WIN) {
            out[idx] = (a > 0.1f) ? a : 0.0f;
            continue;
        }
        int n = (int)(idx >> 12), m = (int)(idx & (N - 1));
        const float* cn = c + (size_t)n * D;
        const float* cm = c + (size_t)m * D;
        double acc[P];
#pragma unroll
        for (int p = 0; p < P; ++p) acc[p] = 0.0;
        for (int d0 = 0; d0 < D; d0 += 4) {
            float4 a4 = *(const float4*)&cn[d0];
            float4 b4 = *(const float4*)&cm[d0];
            float av[4] = {a4.x, a4.y, a4.z, a4.w};
            float bv[4] = {b4.x, b4.y, b4.z, b4.w};
#pragma unroll
            for (int q = 0; q < 4; ++q) {
                double pr = (double)av[q] * (double)bv[q];
#pragma unroll
                for (int p = 0; p < P; ++p) acc[p] += pr * w2[(d0 + q) * P + p];
            }
        }
        double t = 0.0;
#pragma unroll
        for (int p = 0; p < P; ++p)
            t += acc[p] * (rnorm[p * N + n] * rnorm[p * N + m]);
        double fin = t * 0.0625;
        out[idx] = (fin > 0.1) ? (float)fin : 0.0f;
    }
}

// ---------------------------------------------------------------------------
// Fallback full-pass mask fix (only if ws too small; proven not taken).
// ---------------------------------------------------------------------------
__global__ __launch_bounds__(256) void k_fix_full(const float* __restrict__ c,
                                                  const float* __restrict__ w,
                                                  const double* __restrict__ rnorm,
                                                  float* __restrict__ out) {
    __shared__ double w2[D * P];
    for (int e = threadIdx.x; e < P * D; e += 256) {
        int p = e >> 7, d = e & 127;
        double wv = (double)w[p * D + d];
        w2[d * P + p] = wv * wv;
    }
    __syncthreads();
    size_t stride = (size_t)gridDim.x * 256;
    for (size_t idx = (size_t)blockIdx.x * 256 + threadIdx.x; idx < (size_t)N * N;
         idx += stride) {
        float a = out[idx];
        if (fabsf(a - 0.1f) >= WIN) {
            out[idx] = (a > 0.1f) ? a : 0.0f;
            continue;
        }
        int n = (int)(idx >> 12), m = (int)(idx & (N - 1));
        const float* cn = c + (size_t)n * D;
        const float* cm = c + (size_t)m * D;
        double acc[P];
#pragma unroll
        for (int p = 0; p < P; ++p) acc[p] = 0.0;
        for (int d0 = 0; d0 < D; d0 += 4) {
            float4 a4 = *(const float4*)&cn[d0];
            float4 b4 = *(const float4*)&cm[d0];
            float av[4] = {a4.x, a4.y, a4.z, a4.w};
            float bv[4] = {b4.x, b4.y, b4.z, b4.w};
#pragma unroll
            for (int q = 0; q < 4; ++q) {
                double pr = (double)av[q] * (double)bv[q];
#pragma unroll
                for (int p = 0; p < P; ++p) acc[p] += pr * w2[(d0 + q) * P + p];
            }
        }
        double t = 0.0;
#pragma unroll
        for (int p = 0; p < P; ++p)
            t += acc[p] * (rnorm[p * N + n] * rnorm[p * N + m]);
        double fin = t * 0.0625;
        out[idx] = (fin > 0.1) ? (float)fin : 0.0f;
    }
}

// ---------------------------------------------------------------------------
extern "C" void kernel_launch(void* const* d_in, const int* in_sizes, int n_in,
                              void* d_out, int out_size, void* d_ws, size_t ws_size,
                              hipStream_t stream) {
    const float* c = (const float*)d_in[0];
    const float* w = (const float*)d_in[1];
    float* out = (float*)d_out;
    char* ws = (char*)d_ws;

    double* rnorm = (double*)ws;                               // 512 KB
    size_t off = (size_t)P * N * 8;
    unsigned* gcnt = (unsigned*)(ws + off);
    unsigned* govf = gcnt + 1;
    unsigned* glist = (unsigned*)(ws + off + 128);             // 4 MB
    half_t* zb = (half_t*)(ws + off + 128 + (size_t)CAP * 4);  // 16 MB
    size_t need = off + 128 + (size_t)CAP * 4 + (size_t)N * KK * 2;

    if (ws_size >= need) {
        k_pack<<<N, 256, 0, stream>>>(c, w, rnorm, zb, gcnt, govf, 1);
        k_gemm<true><<<NBLK, 512, 0, stream>>>(zb, out, gcnt, govf, glist);
        k_fix2<<<1024, 256, 0, stream>>>(c, w, rnorm, gcnt, glist, out);
        k_guard<<<1024, 256, 0, stream>>>(c, w, rnorm, govf, out);
    } else {
        half_t* zb2 = (half_t*)(ws + off);
        k_pack<<<N, 256, 0, stream>>>(c, w, rnorm, zb2, nullptr, nullptr, 0);
        k_gemm<false><<<NBLK, 512, 0, stream>>>(zb2, out, nullptr, nullptr, nullptr);
        k_fix_full<<<4096, 256, 0, stream>>>(c, w, rnorm, out);
    }
}